// Round 1
// baseline (404.125 us; speedup 1.0000x reference)
//
#include <hip/hip_runtime.h>
#include <cstdint>
#include <cstddef>

// ---------------------------------------------------------------------------
// cross_attention: b=8, c=32, 252x252, ws=8 -> padded 256x256.
// tokens l=(i1,j1) in 32x32, features d'=(i0*256 + j0*32 + c) in 2048.
// Pipeline: norms -> pack (bf16 Qh[l][d'], Kh[l][d'], Vt[d'][l]) ->
//           S = Qh Kh^T * 2048^-0.5 (bf16) -> softmax rows (in place) ->
//           Ot[d'][l] = Vt P^T with fused scatter/crop epilogue.
// ---------------------------------------------------------------------------

typedef __bf16 bf16x8 __attribute__((ext_vector_type(8)));
typedef float  f32x4  __attribute__((ext_vector_type(4)));

__device__ __forceinline__ unsigned short f2bf(float f) {
  unsigned int u = __builtin_bit_cast(unsigned int, f);
  u += 0x7FFFu + ((u >> 16) & 1u);   // round-to-nearest-even
  return (unsigned short)(u >> 16);
}
__device__ __forceinline__ float bf2f(unsigned short h) {
  return __builtin_bit_cast(float, (unsigned int)h << 16);
}

// ---------------------------------------------------------------------------
// Kernel 1: column norms. Block = (t, b, c, i0): 256 threads, each thread owns
// one padded w column, loops 32 rows; then 8 j0-group reductions.
// scales[t][b][d'] = 1 / max(sqrt(sumsq), 1e-12)
// ---------------------------------------------------------------------------
__global__ void norm_kernel(const float* __restrict__ q,
                            const float* __restrict__ k,
                            const float* __restrict__ v,
                            float* __restrict__ scales) {
  int bx = blockIdx.x;
  int t   = bx >> 11;          // 0..2
  int rem = bx & 2047;
  int b   = rem >> 8;          // 0..7
  int c   = (rem >> 3) & 31;   // 0..31
  int i0  = rem & 7;           // 0..7
  const float* x = (t == 0) ? q : (t == 1) ? k : v;
  const float* base = x + ((size_t)b * 32 + c) * 63504;  // 252*252

  int tid = threadIdx.x;
  int w = (tid < 252) ? tid : 502 - tid;   // reflect pad
  float s = 0.f;
  #pragma unroll 4
  for (int i1 = 0; i1 < 32; i1++) {
    int h = i0 * 32 + i1;
    int hs = (h < 252) ? h : 502 - h;
    float val = base[(size_t)hs * 252 + w];
    s += val * val;
  }
  __shared__ float red[256];
  red[tid] = s;
  __syncthreads();
  if (tid < 8) {  // j0 = tid
    float acc = 0.f;
    #pragma unroll
    for (int i = 0; i < 32; i++) acc += red[tid * 32 + i];
    float n = sqrtf(acc);
    float sc = 1.0f / fmaxf(n, 1e-12f);
    scales[((size_t)(t * 8 + b)) * 2048 + i0 * 256 + tid * 32 + c] = sc;
  }
}

// ---------------------------------------------------------------------------
// Kernel 2: normalize + pack to bf16. Block = (t, b, i0, i1): loads one padded
// image row (all 32 channels, 256 padded w) scaled into LDS, then writes:
//  t<2 : X[b][l][d'] rows (d'-contiguous, 16B chunks)  (Qh / Kh)
//  t==2: Vt[b][d'][l] rows (l-contiguous, 64B per thread)
// ---------------------------------------------------------------------------
__global__ void pack_kernel(const float* __restrict__ q,
                            const float* __restrict__ k,
                            const float* __restrict__ v,
                            const float* __restrict__ scales,
                            unsigned short* __restrict__ Qh,
                            unsigned short* __restrict__ Kh,
                            unsigned short* __restrict__ Vt) {
  int bx = blockIdx.x;
  int t   = bx >> 11;
  int rem = bx & 2047;
  int b   = rem >> 8;
  int i0  = (rem >> 5) & 7;
  int i1  = rem & 31;
  const float* x = (t == 0) ? q : (t == 1) ? k : v;

  __shared__ unsigned short tile[32 * 256];  // [c][w_pad]
  __shared__ float scl[256];                 // [j0*32+c]

  int tid = threadIdx.x;
  scl[tid] = scales[((size_t)(t * 8 + b)) * 2048 + i0 * 256 + tid];
  __syncthreads();

  int h  = i0 * 32 + i1;
  int hs = (h < 252) ? h : 502 - h;
  int w  = tid;
  int wsrc = (w < 252) ? w : 502 - w;
  int j0 = w >> 5;
  const float* xb = x + (size_t)b * 32 * 63504;
  #pragma unroll 4
  for (int c = 0; c < 32; c++) {
    float val = xb[(size_t)c * 63504 + (size_t)hs * 252 + wsrc] * scl[j0 * 32 + c];
    tile[c * 256 + w] = f2bf(val);
  }
  __syncthreads();

  if (t < 2) {
    unsigned short* X = ((t == 0) ? Qh : Kh) + (size_t)b * 1024 * 2048;
    #pragma unroll
    for (int r = 0; r < 4; r++) {
      int g  = r * 2048 + tid * 8;   // 32 tokens * 256 feats / 8
      int j1 = g >> 8;
      int p0 = g & 255;              // p = j0*32 + c, c0 in {0,8,16,24}
      int j0w = p0 >> 5;
      int c0  = p0 & 31;
      unsigned int ov[4];
      #pragma unroll
      for (int m = 0; m < 4; m++) {
        unsigned int lo = tile[(c0 + 2 * m)     * 256 + j0w * 32 + j1];
        unsigned int hi = tile[(c0 + 2 * m + 1) * 256 + j0w * 32 + j1];
        ov[m] = lo | (hi << 16);
      }
      int l = i1 * 32 + j1;
      uint4 o4; o4.x = ov[0]; o4.y = ov[1]; o4.z = ov[2]; o4.w = ov[3];
      *(uint4*)&X[(size_t)l * 2048 + i0 * 256 + p0] = o4;
    }
  } else {
    unsigned short* V = Vt + (size_t)b * 2048 * 1024;
    int rrow = tid;                 // p index
    int c   = rrow & 31;
    int j0r = rrow >> 5;
    unsigned short* dst = &V[(size_t)(i0 * 256 + rrow) * 1024 + i1 * 32];
    const unsigned short* src = &tile[c * 256 + j0r * 32];
    #pragma unroll
    for (int m = 0; m < 4; m++) {
      *(uint4*)&dst[m * 8] = *(const uint4*)&src[m * 8];
    }
  }
}

// ---------------------------------------------------------------------------
// GEMM NT: C[M][N] = A[M][K] * B[N][K]^T, bf16 in, fp32 acc.
// 128x128 tile, 4 waves (2x2), each wave 4x4 of mfma_f32_16x16x32_bf16.
// MODE 0: store bf16 S[row][col] * scale  (batch stride 1024*1024)
// MODE 1: scatter fp32 to output with crop (row=d', col=l)
// ---------------------------------------------------------------------------
template <int MODE>
__global__ __launch_bounds__(256, 2)
void gemm_nt(const unsigned short* __restrict__ A,
             const unsigned short* __restrict__ B,
             int K, int Asb, int Bsb, void* __restrict__ Cout, float scale) {
  __shared__ unsigned short lA[128 * 72];  // row stride 72 (=64+8) -> 144B, 16B aligned
  __shared__ unsigned short lB[128 * 72];

  const int tid  = threadIdx.x;
  const int lane = tid & 63;
  const int wave = tid >> 6;
  const int ln15 = lane & 15;
  const int q4   = lane >> 4;
  const int wm   = wave >> 1;
  const int wn   = wave & 1;
  const int m0   = blockIdx.y * 128;
  const int n0   = blockIdx.x * 128;
  const unsigned short* Ab = A + (size_t)blockIdx.z * Asb;
  const unsigned short* Bb = B + (size_t)blockIdx.z * Bsb;

  f32x4 acc[4][4] = {};

  for (int k0 = 0; k0 < K; k0 += 64) {
    #pragma unroll
    for (int r = 0; r < 4; r++) {
      int id  = r * 256 + tid;
      int row = id >> 3;
      int kc  = id & 7;
      uint4 va = *(const uint4*)&Ab[(size_t)(m0 + row) * K + k0 + kc * 8];
      uint4 vb = *(const uint4*)&Bb[(size_t)(n0 + row) * K + k0 + kc * 8];
      *(uint4*)&lA[row * 72 + kc * 8] = va;
      *(uint4*)&lB[row * 72 + kc * 8] = vb;
    }
    __syncthreads();
    #pragma unroll
    for (int kk = 0; kk < 64; kk += 32) {
      bf16x8 af[4], bfr[4];
      #pragma unroll
      for (int mt = 0; mt < 4; mt++)
        af[mt] = *(const bf16x8*)&lA[(wm * 64 + mt * 16 + ln15) * 72 + kk + q4 * 8];
      #pragma unroll
      for (int nt = 0; nt < 4; nt++)
        bfr[nt] = *(const bf16x8*)&lB[(wn * 64 + nt * 16 + ln15) * 72 + kk + q4 * 8];
      #pragma unroll
      for (int mt = 0; mt < 4; mt++)
        #pragma unroll
        for (int nt = 0; nt < 4; nt++)
          acc[mt][nt] = __builtin_amdgcn_mfma_f32_16x16x32_bf16(
              af[mt], bfr[nt], acc[mt][nt], 0, 0, 0);
    }
    __syncthreads();
  }

  if (MODE == 0) {
    unsigned short* Sb = (unsigned short*)Cout + (size_t)blockIdx.z * 1024 * 1024;
    #pragma unroll
    for (int mt = 0; mt < 4; mt++) {
      #pragma unroll
      for (int nt = 0; nt < 4; nt++) {
        int col = n0 + wn * 64 + nt * 16 + ln15;
        #pragma unroll
        for (int rg = 0; rg < 4; rg++) {
          int rowi = m0 + wm * 64 + mt * 16 + q4 * 4 + rg;
          Sb[(size_t)rowi * 1024 + col] = f2bf(acc[mt][nt][rg] * scale);
        }
      }
    }
  } else {
    float* Ob = (float*)Cout;
    int bb = blockIdx.z;
    #pragma unroll
    for (int mt = 0; mt < 4; mt++) {
      #pragma unroll
      for (int nt = 0; nt < 4; nt++) {
        int l  = n0 + wn * 64 + nt * 16 + ln15;
        int i1 = l >> 5, j1 = l & 31;
        #pragma unroll
        for (int rg = 0; rg < 4; rg++) {
          int dp = m0 + wm * 64 + mt * 16 + q4 * 4 + rg;  // d'
          int c  = dp & 31;
          int j0 = (dp >> 5) & 7;
          int i0 = dp >> 8;
          int h = i0 * 32 + i1;
          int w = j0 * 32 + j1;
          if (h < 252 && w < 252)
            Ob[(((size_t)bb * 32 + c) * 252 + h) * 252 + w] = acc[mt][nt][rg];
        }
      }
    }
  }
}

// ---------------------------------------------------------------------------
// Kernel 4: row softmax over S (bf16, in place -> P). Block per row (b,l).
// ---------------------------------------------------------------------------
__global__ void softmax_kernel(unsigned short* __restrict__ S) {
  unsigned short* row = S + (size_t)blockIdx.x * 1024;
  int tid  = threadIdx.x;
  int lane = tid & 63;
  int wid  = tid >> 6;

  uint2 u = *(const uint2*)&row[tid * 4];
  float x0 = bf2f((unsigned short)(u.x & 0xFFFF));
  float x1 = bf2f((unsigned short)(u.x >> 16));
  float x2 = bf2f((unsigned short)(u.y & 0xFFFF));
  float x3 = bf2f((unsigned short)(u.y >> 16));

  __shared__ float red[8];
  float mx = fmaxf(fmaxf(x0, x1), fmaxf(x2, x3));
  #pragma unroll
  for (int off = 32; off > 0; off >>= 1) mx = fmaxf(mx, __shfl_down(mx, off));
  if (lane == 0) red[wid] = mx;
  __syncthreads();
  if (tid == 0)
    red[4] = fmaxf(fmaxf(red[0], red[1]), fmaxf(red[2], red[3]));
  __syncthreads();
  float bm = red[4];

  float e0 = __expf(x0 - bm), e1 = __expf(x1 - bm);
  float e2 = __expf(x2 - bm), e3 = __expf(x3 - bm);
  float s = e0 + e1 + e2 + e3;
  #pragma unroll
  for (int off = 32; off > 0; off >>= 1) s += __shfl_down(s, off);
  if (lane == 0) red[wid] = s;
  __syncthreads();
  if (tid == 0) red[5] = 1.0f / (red[0] + red[1] + red[2] + red[3]);
  __syncthreads();
  float inv = red[5];

  unsigned int o0 = (unsigned int)f2bf(e0 * inv) | ((unsigned int)f2bf(e1 * inv) << 16);
  unsigned int o1 = (unsigned int)f2bf(e2 * inv) | ((unsigned int)f2bf(e3 * inv) << 16);
  uint2 o; o.x = o0; o.y = o1;
  *(uint2*)&row[tid * 4] = o;
}

// ---------------------------------------------------------------------------
extern "C" void kernel_launch(void* const* d_in, const int* in_sizes, int n_in,
                              void* d_out, int out_size, void* d_ws, size_t ws_size,
                              hipStream_t stream) {
  const float* q = (const float*)d_in[0];
  const float* k = (const float*)d_in[1];
  const float* v = (const float*)d_in[2];
  float* out = (float*)d_out;

  char* ws = (char*)d_ws;
  float* scales = (float*)ws;                                   // 3*8*2048*4 = 196608 B
  unsigned short* Qh = (unsigned short*)(ws + 196608);          // 8*1024*2048*2 = 32 MB
  unsigned short* Kh = Qh + (size_t)8 * 1024 * 2048;            // 32 MB
  unsigned short* Vt = Kh + (size_t)8 * 1024 * 2048;            // 32 MB
  unsigned short* S  = Vt + (size_t)8 * 2048 * 1024;            // 8*1024*1024*2 = 16 MB
  // total ws use ~112.2 MB

  const float SIM_SCALE = 0.02209708691207961f;  // 2048^-0.5

  norm_kernel<<<6144, 256, 0, stream>>>(q, k, v, scales);
  pack_kernel<<<6144, 256, 0, stream>>>(q, k, v, scales, Qh, Kh, Vt);
  gemm_nt<0><<<dim3(8, 8, 8), 256, 0, stream>>>(
      Qh, Kh, 2048, 1024 * 2048, 1024 * 2048, (void*)S, SIM_SCALE);
  softmax_kernel<<<8192, 256, 0, stream>>>(S);
  gemm_nt<1><<<dim3(8, 16, 8), 256, 0, stream>>>(
      Vt, S, 1024, 2048 * 1024, 1024 * 1024, (void*)out, 1.0f);
}

// Round 2
// 392.022 us; speedup vs baseline: 1.0309x; 1.0309x over previous
//
#include <hip/hip_runtime.h>
#include <cstdint>
#include <cstddef>

// ---------------------------------------------------------------------------
// cross_attention: b=8, c=32, 252x252, ws=8 -> padded 256x256.
// tokens l=(i1,j1) in 32x32, features d'=(i0*256 + j0*32 + c) in 2048.
// Pipeline: norms -> pack (bf16 Qh[l][d'], Kh[l][d'], Vt[d'][l]) ->
//           S = Qh Kh^T * 2048^-0.5 (bf16) -> softmax rows (in place) ->
//           Ot[d'][l] = Vt P^T with fused scatter/crop epilogue.
// ---------------------------------------------------------------------------

typedef __bf16 bf16x8 __attribute__((ext_vector_type(8)));
typedef float  f32x4  __attribute__((ext_vector_type(4)));

__device__ __forceinline__ unsigned int f2bf(float f) {
  unsigned int u = __builtin_bit_cast(unsigned int, f);
  u += 0x7FFFu + ((u >> 16) & 1u);   // round-to-nearest-even
  return u >> 16;
}
__device__ __forceinline__ float bf2f(unsigned short h) {
  return __builtin_bit_cast(float, (unsigned int)h << 16);
}

__device__ __forceinline__ void load_lds16(const void* g, void* l) {
  __builtin_amdgcn_global_load_lds(
      (const __attribute__((address_space(1))) void*)g,
      (__attribute__((address_space(3))) void*)l, 16, 0, 0);
}

// ---------------------------------------------------------------------------
// Kernel 1: column norms. Block = (t, b, c, i0). 256 threads.
// Thread (i1base = tid>>6, chunk = tid&63) reads float4 cols [chunk*4..+3]
// over 8 rows (i1 = r*4 + i1base). Reflect padding handled by WEIGHTS:
// mirrored rows/cols h,w in [247,250] of the i0==7 / j0==7 windows count 2x;
// padded rows/cols >=252 are never loaded. scales = 1/max(norm,1e-12).
// ---------------------------------------------------------------------------
__global__ void norm_kernel(const float* __restrict__ q,
                            const float* __restrict__ k,
                            const float* __restrict__ v,
                            float* __restrict__ scales) {
  int bx = blockIdx.x;
  int t   = bx >> 11;          // 0..2
  int rem = bx & 2047;
  int b   = rem >> 8;          // 0..7
  int c   = (rem >> 3) & 31;   // 0..31
  int i0  = rem & 7;           // 0..7
  const float* x = (t == 0) ? q : (t == 1) ? k : v;
  const float* base = x + ((size_t)b * 32 + c) * 63504;  // 252*252

  int tid   = threadIdx.x;
  int chunk = tid & 63;        // 4-wide column chunk
  int i1b   = tid >> 6;        // 0..3

  float cw0 = 1.f, cw1 = 1.f, cw2 = 1.f, cw3 = 1.f;
  bool skipc = false;
  if (chunk == 61) cw3 = 2.f;                       // col 247
  else if (chunk == 62) { cw0 = cw1 = cw2 = 2.f; }  // cols 248..250
  else if (chunk == 63) skipc = true;               // cols 252..255 (pure pad)

  float s = 0.f;
  if (!skipc) {
    #pragma unroll
    for (int r = 0; r < 8; r++) {
      int i1 = r * 4 + i1b;
      int h  = i0 * 32 + i1;
      if (h < 252) {
        float rw = (i0 == 7 && h >= 247 && h <= 250) ? 2.f : 1.f;
        float4 vv = *(const float4*)&base[(size_t)h * 252 + chunk * 4];
        s += rw * (cw0 * vv.x * vv.x + cw1 * vv.y * vv.y +
                   cw2 * vv.z * vv.z + cw3 * vv.w * vv.w);
      }
    }
  }
  __shared__ float red[256];
  red[tid] = s;
  __syncthreads();
  if (tid < 8) {  // tid = j0
    float acc = 0.f;
    #pragma unroll
    for (int w = 0; w < 4; w++)
      #pragma unroll
      for (int e = 0; e < 8; e++) acc += red[w * 64 + tid * 8 + e];
    float sc = 1.0f / fmaxf(sqrtf(acc), 1e-12f);
    scales[((size_t)(t * 8 + b)) * 2048 + i0 * 256 + tid * 32 + c] = sc;
  }
}

// ---------------------------------------------------------------------------
// Kernel 2: normalize + pack to bf16. Block = (t, b, i0, i1): one padded image
// row (32 c x 256 w) -> LDS, then:
//  t<2 : X[b][l][d'] rows (d'-contiguous 16B chunks)  (Qh / Kh)
//  t==2: Vt[b][d'][l] rows (l-contiguous 64B per thread)
// Loads are float4; only the chunk-63 tail does the reflect gather.
// ---------------------------------------------------------------------------
__global__ void pack_kernel(const float* __restrict__ q,
                            const float* __restrict__ k,
                            const float* __restrict__ v,
                            const float* __restrict__ scales,
                            unsigned short* __restrict__ Qh,
                            unsigned short* __restrict__ Kh,
                            unsigned short* __restrict__ Vt) {
  int bx = blockIdx.x;
  int t   = bx >> 11;
  int rem = bx & 2047;
  int b   = rem >> 8;
  int i0  = (rem >> 5) & 7;
  int i1  = rem & 31;
  const float* x = (t == 0) ? q : (t == 1) ? k : v;

  __shared__ unsigned short tile[32 * 256];  // [c][w_pad]
  __shared__ float scl[256];                 // [j0*32+c]

  int tid = threadIdx.x;
  scl[tid] = scales[((size_t)(t * 8 + b)) * 2048 + i0 * 256 + tid];
  __syncthreads();

  int h  = i0 * 32 + i1;
  int hs = (h < 252) ? h : 502 - h;
  const float* xb = x + (size_t)b * 32 * 63504 + (size_t)hs * 252;

  #pragma unroll
  for (int r = 0; r < 8; r++) {
    int idx   = r * 256 + tid;
    int c     = idx >> 6;         // 0..31
    int chunk = idx & 63;         // 4-wide w chunk
    const float* src = xb + (size_t)c * 63504;
    if (chunk < 63) {
      float sc = scl[(chunk >> 3) * 32 + c];
      float4 vv = *(const float4*)&src[chunk * 4];
      uint2 o;
      o.x = f2bf(vv.x * sc) | (f2bf(vv.y * sc) << 16);
      o.y = f2bf(vv.z * sc) | (f2bf(vv.w * sc) << 16);
      *(uint2*)&tile[c * 256 + chunk * 4] = o;
    } else {
      float sc = scl[7 * 32 + c];
      // padded cols 252..255 mirror to 250,249,248,247
      float a0 = src[250], a1 = src[249], a2 = src[248], a3 = src[247];
      uint2 o;
      o.x = f2bf(a0 * sc) | (f2bf(a1 * sc) << 16);
      o.y = f2bf(a2 * sc) | (f2bf(a3 * sc) << 16);
      *(uint2*)&tile[c * 256 + 252] = o;
    }
  }
  __syncthreads();

  if (t < 2) {
    unsigned short* X = ((t == 0) ? Qh : Kh) + (size_t)b * 1024 * 2048;
    #pragma unroll
    for (int r = 0; r < 4; r++) {
      int g  = r * 2048 + tid * 8;
      int j1 = g >> 8;
      int p0 = g & 255;              // p = j0*32 + c
      int j0w = p0 >> 5;
      int c0  = p0 & 31;
      unsigned int ov[4];
      #pragma unroll
      for (int m = 0; m < 4; m++) {
        unsigned int lo = tile[(c0 + 2 * m)     * 256 + j0w * 32 + j1];
        unsigned int hi = tile[(c0 + 2 * m + 1) * 256 + j0w * 32 + j1];
        ov[m] = lo | (hi << 16);
      }
      int l = i1 * 32 + j1;
      uint4 o4; o4.x = ov[0]; o4.y = ov[1]; o4.z = ov[2]; o4.w = ov[3];
      *(uint4*)&X[(size_t)l * 2048 + i0 * 256 + p0] = o4;
    }
  } else {
    unsigned short* V = Vt + (size_t)b * 2048 * 1024;
    int rrow = tid;                 // p index
    int c   = rrow & 31;
    int j0r = rrow >> 5;
    unsigned short* dst = &V[(size_t)(i0 * 256 + rrow) * 1024 + i1 * 32];
    const unsigned short* src = &tile[c * 256 + j0r * 32];
    #pragma unroll
    for (int m = 0; m < 4; m++) {
      *(uint4*)&dst[m * 8] = *(const uint4*)&src[m * 8];
    }
  }
}

// ---------------------------------------------------------------------------
// GEMM NT: C[M][N] = A[M][K] * B[N][K]^T, bf16 in, fp32 acc.
// 128x128 tile, 4 waves (2x2), each wave 4x4 of mfma_f32_16x16x32_bf16.
// Staging: global_load_lds width=16, unpadded 64-short rows, XOR-swizzled
// source so LDS phys chunk = logical chunk ^ (row&7) -> conflict-free reads.
// MODE 0: store bf16 S[row][col] * scale  (batch stride 1024*1024)
// MODE 1: scatter fp32 to output with crop (row=d', col=l)
// ---------------------------------------------------------------------------
template <int MODE>
__global__ __launch_bounds__(256, 4)
void gemm_nt(const unsigned short* __restrict__ A,
             const unsigned short* __restrict__ B,
             int K, int Asb, int Bsb, void* __restrict__ Cout, float scale) {
  __shared__ unsigned short lA[128 * 64];  // 16 KB, no padding (global_load_lds)
  __shared__ unsigned short lB[128 * 64];

  const int tid  = threadIdx.x;
  const int lane = tid & 63;
  const int wave = tid >> 6;
  const int ln15 = lane & 15;
  const int q4   = lane >> 4;
  const int wm   = wave >> 1;
  const int wn   = wave & 1;
  const int m0   = blockIdx.y * 128;
  const int n0   = blockIdx.x * 128;
  const unsigned short* Ab = A + (size_t)blockIdx.z * Asb;
  const unsigned short* Bb = B + (size_t)blockIdx.z * Bsb;

  const int srow = lane >> 3;       // row within 8-row staging group
  const int kcp  = lane & 7;        // physical 16B chunk (LDS dest = lane*16)
  const int kcl  = kcp ^ srow;      // logical chunk fetched (xor swizzle)

  f32x4 acc[4][4] = {};

  for (int k0 = 0; k0 < K; k0 += 64) {
    #pragma unroll
    for (int r = 0; r < 4; r++) {
      int rowg = wave * 32 + r * 8;                 // wave-uniform row base
      int row  = rowg + srow;
      load_lds16(&Ab[(size_t)(m0 + row) * K + k0 + kcl * 8], &lA[rowg * 64]);
      load_lds16(&Bb[(size_t)(n0 + row) * K + k0 + kcl * 8], &lB[rowg * 64]);
    }
    __syncthreads();
    #pragma unroll
    for (int kk = 0; kk < 2; kk++) {
      bf16x8 af[4], bfr[4];
      #pragma unroll
      for (int mt = 0; mt < 4; mt++) {
        int row = wm * 64 + mt * 16 + ln15;
        int pc  = (kk * 4 + q4) ^ (row & 7);
        af[mt] = *(const bf16x8*)&lA[row * 64 + pc * 8];
      }
      #pragma unroll
      for (int nt = 0; nt < 4; nt++) {
        int row = wn * 64 + nt * 16 + ln15;
        int pc  = (kk * 4 + q4) ^ (row & 7);
        bfr[nt] = *(const bf16x8*)&lB[row * 64 + pc * 8];
      }
      #pragma unroll
      for (int mt = 0; mt < 4; mt++)
        #pragma unroll
        for (int nt = 0; nt < 4; nt++)
          acc[mt][nt] = __builtin_amdgcn_mfma_f32_16x16x32_bf16(
              af[mt], bfr[nt], acc[mt][nt], 0, 0, 0);
    }
    __syncthreads();
  }

  if (MODE == 0) {
    unsigned short* Sb = (unsigned short*)Cout + (size_t)blockIdx.z * 1024 * 1024;
    #pragma unroll
    for (int mt = 0; mt < 4; mt++) {
      #pragma unroll
      for (int nt = 0; nt < 4; nt++) {
        int col = n0 + wn * 64 + nt * 16 + ln15;
        #pragma unroll
        for (int rg = 0; rg < 4; rg++) {
          int rowi = m0 + wm * 64 + mt * 16 + q4 * 4 + rg;
          Sb[(size_t)rowi * 1024 + col] = (unsigned short)f2bf(acc[mt][nt][rg] * scale);
        }
      }
    }
  } else {
    float* Ob = (float*)Cout;
    int bb = blockIdx.z;
    #pragma unroll
    for (int mt = 0; mt < 4; mt++) {
      #pragma unroll
      for (int nt = 0; nt < 4; nt++) {
        int l  = n0 + wn * 64 + nt * 16 + ln15;
        int i1 = l >> 5, j1 = l & 31;
        #pragma unroll
        for (int rg = 0; rg < 4; rg++) {
          int dp = m0 + wm * 64 + mt * 16 + q4 * 4 + rg;  // d'
          int c  = dp & 31;
          int j0 = (dp >> 5) & 7;
          int i0 = dp >> 8;
          int h = i0 * 32 + i1;
          int w = j0 * 32 + j1;
          if (h < 252 && w < 252)
            Ob[(((size_t)bb * 32 + c) * 252 + h) * 252 + w] = acc[mt][nt][rg];
        }
      }
    }
  }
}

// ---------------------------------------------------------------------------
// Kernel 4: row softmax over S (bf16, in place -> P). Block per row (b,l).
// ---------------------------------------------------------------------------
__global__ void softmax_kernel(unsigned short* __restrict__ S) {
  unsigned short* row = S + (size_t)blockIdx.x * 1024;
  int tid  = threadIdx.x;
  int lane = tid & 63;
  int wid  = tid >> 6;

  uint2 u = *(const uint2*)&row[tid * 4];
  float x0 = bf2f((unsigned short)(u.x & 0xFFFF));
  float x1 = bf2f((unsigned short)(u.x >> 16));
  float x2 = bf2f((unsigned short)(u.y & 0xFFFF));
  float x3 = bf2f((unsigned short)(u.y >> 16));

  __shared__ float red[8];
  float mx = fmaxf(fmaxf(x0, x1), fmaxf(x2, x3));
  #pragma unroll
  for (int off = 32; off > 0; off >>= 1) mx = fmaxf(mx, __shfl_down(mx, off));
  if (lane == 0) red[wid] = mx;
  __syncthreads();
  if (tid == 0)
    red[4] = fmaxf(fmaxf(red[0], red[1]), fmaxf(red[2], red[3]));
  __syncthreads();
  float bm = red[4];

  float e0 = __expf(x0 - bm), e1 = __expf(x1 - bm);
  float e2 = __expf(x2 - bm), e3 = __expf(x3 - bm);
  float s = e0 + e1 + e2 + e3;
  #pragma unroll
  for (int off = 32; off > 0; off >>= 1) s += __shfl_down(s, off);
  if (lane == 0) red[wid] = s;
  __syncthreads();
  if (tid == 0) red[5] = 1.0f / (red[0] + red[1] + red[2] + red[3]);
  __syncthreads();
  float inv = red[5];

  unsigned int o0 = f2bf(e0 * inv) | (f2bf(e1 * inv) << 16);
  unsigned int o1 = f2bf(e2 * inv) | (f2bf(e3 * inv) << 16);
  uint2 o; o.x = o0; o.y = o1;
  *(uint2*)&row[tid * 4] = o;
}

// ---------------------------------------------------------------------------
extern "C" void kernel_launch(void* const* d_in, const int* in_sizes, int n_in,
                              void* d_out, int out_size, void* d_ws, size_t ws_size,
                              hipStream_t stream) {
  const float* q = (const float*)d_in[0];
  const float* k = (const float*)d_in[1];
  const float* v = (const float*)d_in[2];
  float* out = (float*)d_out;

  char* ws = (char*)d_ws;
  float* scales = (float*)ws;                                   // 196608 B
  unsigned short* Qh = (unsigned short*)(ws + 196608);          // 32 MB
  unsigned short* Kh = Qh + (size_t)8 * 1024 * 2048;            // 32 MB
  unsigned short* Vt = Kh + (size_t)8 * 1024 * 2048;            // 32 MB
  unsigned short* S  = Vt + (size_t)8 * 2048 * 1024;            // 16 MB

  const float SIM_SCALE = 0.02209708691207961f;  // 2048^-0.5

  norm_kernel<<<6144, 256, 0, stream>>>(q, k, v, scales);
  pack_kernel<<<6144, 256, 0, stream>>>(q, k, v, scales, Qh, Kh, Vt);
  gemm_nt<0><<<dim3(8, 8, 8), 256, 0, stream>>>(
      Qh, Kh, 2048, 1024 * 2048, 1024 * 2048, (void*)S, SIM_SCALE);
  softmax_kernel<<<8192, 256, 0, stream>>>(S);
  gemm_nt<1><<<dim3(8, 16, 8), 256, 0, stream>>>(
      Vt, S, 1024, 2048 * 1024, 1024 * 1024, (void*)out, 1.0f);
}

// Round 3
// 384.621 us; speedup vs baseline: 1.0507x; 1.0192x over previous
//
#include <hip/hip_runtime.h>
#include <cstdint>
#include <cstddef>

// ---------------------------------------------------------------------------
// cross_attention: b=8, c=32, 252x252, ws=8 -> padded 256x256.
// tokens l=(i1,j1) in 32x32, features d'=(i0*256 + j0*32 + c) in 2048.
// Pipeline: norms -> pack (bf16 Qh[l][d'], Kh[l][d'], Vt[d'][l]) ->
//           S = Qh Kh^T * 2048^-0.5 (bf16) -> softmax rows (in place) ->
//           Ot[d'][l] = Vt P^T with fused scatter/crop epilogue.
// ---------------------------------------------------------------------------

typedef __bf16 bf16x8 __attribute__((ext_vector_type(8)));
typedef float  f32x4  __attribute__((ext_vector_type(4)));

__device__ __forceinline__ unsigned int f2bf(float f) {
  unsigned int u = __builtin_bit_cast(unsigned int, f);
  u += 0x7FFFu + ((u >> 16) & 1u);   // round-to-nearest-even
  return u >> 16;
}
__device__ __forceinline__ float bf2f(unsigned short h) {
  return __builtin_bit_cast(float, (unsigned int)h << 16);
}

__device__ __forceinline__ void load_lds16(const void* g, void* l) {
  __builtin_amdgcn_global_load_lds(
      (const __attribute__((address_space(1))) void*)g,
      (__attribute__((address_space(3))) void*)l, 16, 0, 0);
}

// ---------------------------------------------------------------------------
// Kernel 1: column norms. Block = (t, b, c, i0). 256 threads.
// Thread (i1b = tid>>6, chunk = tid&63) reads float4 cols [chunk*4..+3].
// Reflect padding by WEIGHTS (rows/cols 247..250 of the last window count 2x,
// pads >= 252 never loaded). Block-uniform i0<7 split keeps loops branch-free
// so loads batch. scales = 1/max(norm,1e-12).
// ---------------------------------------------------------------------------
__global__ void norm_kernel(const float* __restrict__ q,
                            const float* __restrict__ k,
                            const float* __restrict__ v,
                            float* __restrict__ scales) {
  int bx = blockIdx.x;
  int t   = bx >> 11;          // 0..2
  int rem = bx & 2047;
  int b   = rem >> 8;          // 0..7
  int c   = (rem >> 3) & 31;   // 0..31
  int i0  = rem & 7;           // 0..7
  const float* x = (t == 0) ? q : (t == 1) ? k : v;
  const float* base = x + ((size_t)b * 32 + c) * 63504;  // 252*252

  int tid   = threadIdx.x;
  int chunk = tid & 63;        // 4-wide column chunk
  int i1b   = tid >> 6;        // 0..3

  float cw0 = 1.f, cw1 = 1.f, cw2 = 1.f, cw3 = 1.f;
  bool skipc = false;
  if (chunk == 61) cw3 = 2.f;                       // col 247
  else if (chunk == 62) { cw0 = cw1 = cw2 = 2.f; }  // cols 248..250
  else if (chunk == 63) skipc = true;               // cols 252..255 (pure pad)

  float s = 0.f;
  if (!skipc) {
    if (i0 < 7) {
      float4 vv[8];
      #pragma unroll
      for (int r = 0; r < 8; r++) {
        int h = i0 * 32 + r * 4 + i1b;
        vv[r] = *(const float4*)&base[(size_t)h * 252 + chunk * 4];
      }
      #pragma unroll
      for (int r = 0; r < 8; r++)
        s += cw0 * vv[r].x * vv[r].x + cw1 * vv[r].y * vv[r].y +
             cw2 * vv[r].z * vv[r].z + cw3 * vv[r].w * vv[r].w;
    } else {
      float4 vv[7];
      #pragma unroll
      for (int r = 0; r < 7; r++) {
        int h = 224 + r * 4 + i1b;   // h <= 251 for r<7
        vv[r] = *(const float4*)&base[(size_t)h * 252 + chunk * 4];
      }
      #pragma unroll
      for (int r = 0; r < 7; r++) {
        int i1 = r * 4 + i1b;
        float rw = ((unsigned)(i1 - 23) <= 3u) ? 2.f : 1.f;  // h in 247..250
        s += rw * (cw0 * vv[r].x * vv[r].x + cw1 * vv[r].y * vv[r].y +
                   cw2 * vv[r].z * vv[r].z + cw3 * vv[r].w * vv[r].w);
      }
    }
  }
  __shared__ float red[256];
  red[tid] = s;
  __syncthreads();
  if (tid < 8) {  // tid = j0
    float acc = 0.f;
    #pragma unroll
    for (int w = 0; w < 4; w++)
      #pragma unroll
      for (int e = 0; e < 8; e++) acc += red[w * 64 + tid * 8 + e];
    float sc = 1.0f / fmaxf(sqrtf(acc), 1e-12f);
    scales[((size_t)(t * 8 + b)) * 2048 + i0 * 256 + tid * 32 + c] = sc;
  }
}

// ---------------------------------------------------------------------------
// Kernel 2: normalize + pack to bf16. Block = (t, b, i0, i1): one padded image
// row (32 c x 256 w), scaled, staged in LDS as FLOATS, then:
//  t<2 : X[b][l][d'] rows (d'-contiguous 16B chunks)  (Qh / Kh)
//        LDS layout: stride 257, within-window rotation pos=((w&31)+j0)&31
//        -> gather-phase scalar reads hit all 32 banks (2/bank, free).
//  t==2: Vt[b][d'][l] rows (l-contiguous 64B per thread)
//        LDS layout: stride 260, unrotated -> b128 uniform 8/bank (min).
// ---------------------------------------------------------------------------
__global__ void pack_kernel(const float* __restrict__ q,
                            const float* __restrict__ k,
                            const float* __restrict__ v,
                            const float* __restrict__ scales,
                            unsigned short* __restrict__ Qh,
                            unsigned short* __restrict__ Kh,
                            unsigned short* __restrict__ Vt) {
  int bx = blockIdx.x;
  int t   = bx >> 11;
  int rem = bx & 2047;
  int b   = rem >> 8;
  int i0  = (rem >> 5) & 7;
  int i1  = rem & 31;
  const float* x = (t == 0) ? q : (t == 1) ? k : v;

  __shared__ float tf[32 * 260];   // 33.3 KB; stride 257 (t<2) or 260 (t==2)
  __shared__ float sclt[256];      // transposed: [c*8 + j0]

  int tid = threadIdx.x;
  // scales[...][i0*256 + p], p = j0*32 + c  ->  sclt[c*8 + j0]
  sclt[(tid & 31) * 8 + (tid >> 5)] =
      scales[((size_t)(t * 8 + b)) * 2048 + i0 * 256 + tid];
  __syncthreads();

  int h  = i0 * 32 + i1;
  int hs = (h < 252) ? h : 502 - h;
  const float* xb = x + (size_t)b * 32 * 63504 + (size_t)hs * 252;

  if (t < 2) {
    // ---- load phase: rotated scalar stores, stride 257 ----
    #pragma unroll
    for (int r = 0; r < 8; r++) {
      int c     = r * 4 + (tid >> 6);
      int chunk = tid & 63;
      const float* src = xb + (size_t)c * 63504;
      int j0 = chunk >> 3, cq = chunk & 7;
      float sc = sclt[c * 8 + j0];
      float4 vv;
      if (chunk < 63) {
        vv = *(const float4*)&src[chunk * 4];
      } else {  // cols 252..255 mirror to 250,249,248,247
        vv.x = src[250]; vv.y = src[249]; vv.z = src[248]; vv.w = src[247];
      }
      float* row = &tf[c * 257 + j0 * 32];
      int p = cq * 4 + j0;
      row[p & 31]       = vv.x * sc;
      row[(p + 1) & 31] = vv.y * sc;
      row[(p + 2) & 31] = vv.z * sc;
      row[(p + 3) & 31] = vv.w * sc;
    }
    __syncthreads();
    // ---- gather phase: rotated scalar reads, coalesced 16B global stores ----
    unsigned short* X = ((t == 0) ? Qh : Kh) + (size_t)b * 1024 * 2048;
    #pragma unroll
    for (int r = 0; r < 4; r++) {
      int g   = r * 2048 + tid * 8;
      int j1  = g >> 8;               // 0..31
      int p0  = g & 255;              // p = j0*32 + c
      int j0w = p0 >> 5;
      int c0  = p0 & 31;
      unsigned int ov[4];
      #pragma unroll
      for (int m = 0; m < 4; m++) {
        float lo = tf[(c0 + 2 * m)     * 257 + j0w * 32 + ((j1 + j0w) & 31)];
        float hi = tf[(c0 + 2 * m + 1) * 257 + j0w * 32 + ((j1 + j0w) & 31)];
        ov[m] = f2bf(lo) | (f2bf(hi) << 16);
      }
      int l = i1 * 32 + j1;
      uint4 o4; o4.x = ov[0]; o4.y = ov[1]; o4.z = ov[2]; o4.w = ov[3];
      *(uint4*)&X[(size_t)l * 2048 + i0 * 256 + p0] = o4;
    }
  } else {
    // ---- load phase: unrotated float4 stores, stride 260 ----
    #pragma unroll
    for (int r = 0; r < 8; r++) {
      int c     = r * 4 + (tid >> 6);
      int chunk = tid & 63;
      const float* src = xb + (size_t)c * 63504;
      int j0 = chunk >> 3;
      float sc = sclt[c * 8 + j0];
      float4 vv;
      if (chunk < 63) {
        vv = *(const float4*)&src[chunk * 4];
      } else {
        vv.x = src[250]; vv.y = src[249]; vv.z = src[248]; vv.w = src[247];
      }
      vv.x *= sc; vv.y *= sc; vv.z *= sc; vv.w *= sc;
      *(float4*)&tf[c * 260 + chunk * 4] = vv;
    }
    __syncthreads();
    // ---- scatter phase: b128 reads (uniform banks), 64B/thread stores ----
    unsigned short* V = Vt + (size_t)b * 2048 * 1024;
    int c   = tid & 31;
    int j0r = tid >> 5;
    unsigned short* dst = &V[(size_t)(i0 * 256 + tid) * 1024 + i1 * 32];
    const float* srcrow = &tf[c * 260 + j0r * 32];
    #pragma unroll
    for (int m = 0; m < 4; m++) {
      float4 a = *(const float4*)&srcrow[m * 8];
      float4 bq = *(const float4*)&srcrow[m * 8 + 4];
      uint4 o4;
      o4.x = f2bf(a.x)  | (f2bf(a.y)  << 16);
      o4.y = f2bf(a.z)  | (f2bf(a.w)  << 16);
      o4.z = f2bf(bq.x) | (f2bf(bq.y) << 16);
      o4.w = f2bf(bq.z) | (f2bf(bq.w) << 16);
      *(uint4*)&dst[m * 8] = o4;
    }
  }
}

// ---------------------------------------------------------------------------
// GEMM NT: C[M][N] = A[M][K] * B[N][K]^T, bf16 in, fp32 acc.
// 128x128 tile, 4 waves (2x2), each wave 4x4 of mfma_f32_16x16x32_bf16.
// Staging: global_load_lds width=16, unpadded 64-short rows, XOR-swizzled
// source so LDS phys chunk = logical chunk ^ (row&7) -> conflict-free reads.
// MODE 0: store bf16 S[row][col] * scale  (batch stride 1024*1024)
// MODE 1: scatter fp32 to output with crop (row=d', col=l)
// ---------------------------------------------------------------------------
template <int MODE>
__global__ __launch_bounds__(256, 4)
void gemm_nt(const unsigned short* __restrict__ A,
             const unsigned short* __restrict__ B,
             int K, int Asb, int Bsb, void* __restrict__ Cout, float scale) {
  __shared__ unsigned short lA[128 * 64];  // 16 KB, no padding (global_load_lds)
  __shared__ unsigned short lB[128 * 64];

  const int tid  = threadIdx.x;
  const int lane = tid & 63;
  const int wave = tid >> 6;
  const int ln15 = lane & 15;
  const int q4   = lane >> 4;
  const int wm   = wave >> 1;
  const int wn   = wave & 1;
  const int m0   = blockIdx.y * 128;
  const int n0   = blockIdx.x * 128;
  const unsigned short* Ab = A + (size_t)blockIdx.z * Asb;
  const unsigned short* Bb = B + (size_t)blockIdx.z * Bsb;

  const int srow = lane >> 3;       // row within 8-row staging group
  const int kcp  = lane & 7;        // physical 16B chunk (LDS dest = lane*16)
  const int kcl  = kcp ^ srow;      // logical chunk fetched (xor swizzle)

  f32x4 acc[4][4] = {};

  for (int k0 = 0; k0 < K; k0 += 64) {
    #pragma unroll
    for (int r = 0; r < 4; r++) {
      int rowg = wave * 32 + r * 8;                 // wave-uniform row base
      int row  = rowg + srow;
      load_lds16(&Ab[(size_t)(m0 + row) * K + k0 + kcl * 8], &lA[rowg * 64]);
      load_lds16(&Bb[(size_t)(n0 + row) * K + k0 + kcl * 8], &lB[rowg * 64]);
    }
    __syncthreads();
    #pragma unroll
    for (int kk = 0; kk < 2; kk++) {
      bf16x8 af[4], bfr[4];
      #pragma unroll
      for (int mt = 0; mt < 4; mt++) {
        int row = wm * 64 + mt * 16 + ln15;
        int pc  = (kk * 4 + q4) ^ (row & 7);
        af[mt] = *(const bf16x8*)&lA[row * 64 + pc * 8];
      }
      #pragma unroll
      for (int nt = 0; nt < 4; nt++) {
        int row = wn * 64 + nt * 16 + ln15;
        int pc  = (kk * 4 + q4) ^ (row & 7);
        bfr[nt] = *(const bf16x8*)&lB[row * 64 + pc * 8];
      }
      #pragma unroll
      for (int mt = 0; mt < 4; mt++)
        #pragma unroll
        for (int nt = 0; nt < 4; nt++)
          acc[mt][nt] = __builtin_amdgcn_mfma_f32_16x16x32_bf16(
              af[mt], bfr[nt], acc[mt][nt], 0, 0, 0);
    }
    __syncthreads();
  }

  if (MODE == 0) {
    unsigned short* Sb = (unsigned short*)Cout + (size_t)blockIdx.z * 1024 * 1024;
    #pragma unroll
    for (int mt = 0; mt < 4; mt++) {
      #pragma unroll
      for (int nt = 0; nt < 4; nt++) {
        int col = n0 + wn * 64 + nt * 16 + ln15;
        #pragma unroll
        for (int rg = 0; rg < 4; rg++) {
          int rowi = m0 + wm * 64 + mt * 16 + q4 * 4 + rg;
          Sb[(size_t)rowi * 1024 + col] = (unsigned short)f2bf(acc[mt][nt][rg] * scale);
        }
      }
    }
  } else {
    float* Ob = (float*)Cout;
    int bb = blockIdx.z;
    #pragma unroll
    for (int mt = 0; mt < 4; mt++) {
      #pragma unroll
      for (int nt = 0; nt < 4; nt++) {
        int l  = n0 + wn * 64 + nt * 16 + ln15;
        int i1 = l >> 5, j1 = l & 31;
        #pragma unroll
        for (int rg = 0; rg < 4; rg++) {
          int dp = m0 + wm * 64 + mt * 16 + q4 * 4 + rg;  // d'
          int c  = dp & 31;
          int j0 = (dp >> 5) & 7;
          int i0 = dp >> 8;
          int h = i0 * 32 + i1;
          int w = j0 * 32 + j1;
          if (h < 252 && w < 252)
            Ob[(((size_t)bb * 32 + c) * 252 + h) * 252 + w] = acc[mt][nt][rg];
        }
      }
    }
  }
}

// ---------------------------------------------------------------------------
// Kernel 4: row softmax over S (bf16, in place -> P). Block per row (b,l).
// ---------------------------------------------------------------------------
__global__ void softmax_kernel(unsigned short* __restrict__ S) {
  unsigned short* row = S + (size_t)blockIdx.x * 1024;
  int tid  = threadIdx.x;
  int lane = tid & 63;
  int wid  = tid >> 6;

  uint2 u = *(const uint2*)&row[tid * 4];
  float x0 = bf2f((unsigned short)(u.x & 0xFFFF));
  float x1 = bf2f((unsigned short)(u.x >> 16));
  float x2 = bf2f((unsigned short)(u.y & 0xFFFF));
  float x3 = bf2f((unsigned short)(u.y >> 16));

  __shared__ float red[8];
  float mx = fmaxf(fmaxf(x0, x1), fmaxf(x2, x3));
  #pragma unroll
  for (int off = 32; off > 0; off >>= 1) mx = fmaxf(mx, __shfl_down(mx, off));
  if (lane == 0) red[wid] = mx;
  __syncthreads();
  if (tid == 0)
    red[4] = fmaxf(fmaxf(red[0], red[1]), fmaxf(red[2], red[3]));
  __syncthreads();
  float bm = red[4];

  float e0 = __expf(x0 - bm), e1 = __expf(x1 - bm);
  float e2 = __expf(x2 - bm), e3 = __expf(x3 - bm);
  float s = e0 + e1 + e2 + e3;
  #pragma unroll
  for (int off = 32; off > 0; off >>= 1) s += __shfl_down(s, off);
  if (lane == 0) red[wid] = s;
  __syncthreads();
  if (tid == 0) red[5] = 1.0f / (red[0] + red[1] + red[2] + red[3]);
  __syncthreads();
  float inv = red[5];

  unsigned int o0 = f2bf(e0 * inv) | (f2bf(e1 * inv) << 16);
  unsigned int o1 = f2bf(e2 * inv) | (f2bf(e3 * inv) << 16);
  uint2 o; o.x = o0; o.y = o1;
  *(uint2*)&row[tid * 4] = o;
}

// ---------------------------------------------------------------------------
extern "C" void kernel_launch(void* const* d_in, const int* in_sizes, int n_in,
                              void* d_out, int out_size, void* d_ws, size_t ws_size,
                              hipStream_t stream) {
  const float* q = (const float*)d_in[0];
  const float* k = (const float*)d_in[1];
  const float* v = (const float*)d_in[2];
  float* out = (float*)d_out;

  char* ws = (char*)d_ws;
  float* scales = (float*)ws;                                   // 196608 B
  unsigned short* Qh = (unsigned short*)(ws + 196608);          // 32 MB
  unsigned short* Kh = Qh + (size_t)8 * 1024 * 2048;            // 32 MB
  unsigned short* Vt = Kh + (size_t)8 * 1024 * 2048;            // 32 MB
  unsigned short* S  = Vt + (size_t)8 * 2048 * 1024;            // 16 MB

  const float SIM_SCALE = 0.02209708691207961f;  // 2048^-0.5

  norm_kernel<<<6144, 256, 0, stream>>>(q, k, v, scales);
  pack_kernel<<<6144, 256, 0, stream>>>(q, k, v, scales, Qh, Kh, Vt);
  gemm_nt<0><<<dim3(8, 8, 8), 256, 0, stream>>>(
      Qh, Kh, 2048, 1024 * 2048, 1024 * 2048, (void*)S, SIM_SCALE);
  softmax_kernel<<<8192, 256, 0, stream>>>(S);
  gemm_nt<1><<<dim3(8, 16, 8), 256, 0, stream>>>(
      Vt, S, 1024, 2048 * 1024, 1024 * 1024, (void*)out, 1.0f);
}